// Round 5
// baseline (272.463 us; speedup 1.0000x reference)
//
#include <hip/hip_runtime.h>
#include <hip/hip_bf16.h>

constexpr int H  = 256;
constexpr int H2 = 128;
constexpr int N  = 1024;
constexpr int T  = 12;
constexpr int B  = 4;
constexpr int M  = B * N; // 4096 rows total

using short8 = __attribute__((ext_vector_type(8))) short;
using f32x4  = __attribute__((ext_vector_type(4))) float;

// fp32 -> bf16 bits, round-to-nearest-even
__device__ __forceinline__ unsigned short f2bf(float f) {
    union { float f; unsigned int u; } v; v.f = f;
    unsigned int u = v.u;
    u += 0x7FFFu + ((u >> 16) & 1u);
    return (unsigned short)(u >> 16);
}

__device__ __forceinline__ uint4 pack8(const float4& f0, const float4& f1) {
    union { unsigned short u[8]; uint4 v; } r;
    r.u[0] = f2bf(f0.x); r.u[1] = f2bf(f0.y); r.u[2] = f2bf(f0.z); r.u[3] = f2bf(f0.w);
    r.u[4] = f2bf(f1.x); r.u[5] = f2bf(f1.y); r.u[6] = f2bf(f1.z); r.u[7] = f2bf(f1.w);
    return r.v;
}

// ---------------- k0: fold Wb + all weight transposes + biases --------------
// grid 897 x 256 threads, role by blockIdx.x:
//   [0,256)   : fold row i: W2T[j][i] = bf16( sum_l W2o[i][l]*Wb[l][j] )
//   256       : biases: bias1=[b1o|b1d]; bias2=[b2o@Wb | b2d]
//   [257,769) : W1T[n][k] = bf16(n<256 ? W1o[k][n] : W1d[k][n-256])
//   [769,897) : W2T[128+m][k] = bf16(W2d[k][m])
__global__ __launch_bounds__(256) void prep_kernel(
    const float* __restrict__ W1o, const float* __restrict__ b1o,
    const float* __restrict__ W2o, const float* __restrict__ b2o,
    const float* __restrict__ W1d, const float* __restrict__ b1d,
    const float* __restrict__ W2d, const float* __restrict__ b2d,
    const float* __restrict__ Wb,
    unsigned short* __restrict__ W1T, unsigned short* __restrict__ W2T,
    float* __restrict__ bias1, float* __restrict__ bias2)
{
    const int bx = blockIdx.x;
    const int t  = threadIdx.x;
    if (bx < 256) {
        __shared__ float row[H2];
        if (t < H2) row[t] = W2o[bx * H2 + t];
        __syncthreads();
        if (t < H2) {
            float acc = 0.f;
#pragma unroll 8
            for (int l = 0; l < H2; ++l) acc = fmaf(row[l], Wb[l * H2 + t], acc);
            W2T[t * H + bx] = f2bf(acc);
        }
    } else if (bx == 256) {
        bias1[t]       = b1o[t];
        bias1[256 + t] = b1d[t];
        if (t < H2) {
            float acc = 0.f;
#pragma unroll 8
            for (int l = 0; l < H2; ++l) acc = fmaf(b2o[l], Wb[l * H2 + t], acc);
            bias2[t] = acc;
        } else {
            bias2[t] = b2d[t - H2];   // t in [128,256)
        }
    } else if (bx < 769) {
        const int n = bx - 257;       // 0..511
        const float v = (n < 256) ? W1o[t * H + n] : W1d[t * H + (n - 256)];
        W1T[n * H + t] = f2bf(v);
    } else {
        const int m = bx - 769;       // 0..127
        W2T[(128 + m) * H + t] = f2bf(W2d[t * H2 + m]);
    }
}

// ---------------- k1: enc1 — h = relu(x @ [W1o|W1d] + bias1) ----------------
// A is fp32, converted to bf16 in-register during staging. 64x64 tile, K=256.
// 4 waves; wave w owns output cols [16w,16w+16).
__global__ __launch_bounds__(256) void enc1_kernel(
    const float* __restrict__ x, const unsigned short* __restrict__ W1T,
    const float* __restrict__ bias1, unsigned short* __restrict__ h)
{
    __shared__ unsigned short Abuf[64 * 40];
    __shared__ unsigned short Bbuf[64 * 40];
    const int tid = threadIdx.x;
    const int w  = tid >> 6;
    const int l  = tid & 63;
    const int lr = tid >> 2;            // staging row 0..63
    const int lk = (tid & 3) * 8;       // staging k offset (elements)

    const float* A = x + ((size_t)blockIdx.y * 64) * H;          // row0
    const unsigned short* Bt = W1T + (size_t)blockIdx.x * 64 * H;
    const float* bias = bias1 + blockIdx.x * 64;
    unsigned short* C = h + ((size_t)blockIdx.y * 64) * 512 + blockIdx.x * 64;

    float4 a0 = *(const float4*)(A + (size_t)lr * H + lk);
    float4 a1 = *(const float4*)(A + (size_t)lr * H + lk + 4);
    uint4  bR = *(const uint4*)(Bt + (size_t)lr * H + lk);

    f32x4 z = {0.f, 0.f, 0.f, 0.f};
    f32x4 acc[4] = {z, z, z, z};

    for (int kc = 0; kc < H; kc += 32) {
        if (kc) __syncthreads();
        *(uint4*)&Abuf[lr * 40 + lk] = pack8(a0, a1);
        *(uint4*)&Bbuf[lr * 40 + lk] = bR;
        __syncthreads();
        if (kc + 32 < H) {
            a0 = *(const float4*)(A + (size_t)lr * H + kc + 32 + lk);
            a1 = *(const float4*)(A + (size_t)lr * H + kc + 32 + lk + 4);
            bR = *(const uint4*)(Bt + (size_t)lr * H + kc + 32 + lk);
        }
        const int q8 = (l >> 4) * 8;
        const short8 bf = *(const short8*)&Bbuf[(w * 16 + (l & 15)) * 40 + q8];
#pragma unroll
        for (int it = 0; it < 4; ++it) {
            const short8 af = *(const short8*)&Abuf[(it * 16 + (l & 15)) * 40 + q8];
            acc[it] = __builtin_amdgcn_mfma_f32_16x16x32_bf16(af, bf, acc[it], 0, 0, 0);
        }
    }

    const int n  = w * 16 + (l & 15);
    const int r0 = (l >> 4) * 4;
    const float bn = bias[n];
#pragma unroll
    for (int it = 0; it < 4; ++it)
#pragma unroll
        for (int r = 0; r < 4; ++r)
            C[(size_t)(it * 16 + r0 + r) * 512 + n] =
                f2bf(fmaxf(acc[it][r] + bn, 0.f));
}

// ---------------- k2: enc2 — od = [oW|dd] = h_branch @ W2T + bias2 ----------
__global__ __launch_bounds__(256) void enc2_kernel(
    const unsigned short* __restrict__ h, const unsigned short* __restrict__ W2T,
    const float* __restrict__ bias2, unsigned short* __restrict__ od)
{
    __shared__ unsigned short Abuf[64 * 40];
    __shared__ unsigned short Bbuf[64 * 40];
    const int tid = threadIdx.x;
    const int w  = tid >> 6;
    const int l  = tid & 63;
    const int lr = tid >> 2;
    const int lk = (tid & 3) * 8;
    const int bx = blockIdx.x;

    const unsigned short* A  = h + ((size_t)blockIdx.y * 64) * 512 + (bx >> 1) * 256;
    const unsigned short* Bt = W2T + (size_t)bx * 64 * H;
    const float* bias = bias2 + bx * 64;
    unsigned short* C = od + ((size_t)blockIdx.y * 64) * 256 + bx * 64;

    uint4 aR = *(const uint4*)(A + (size_t)lr * 512 + lk);
    uint4 bR = *(const uint4*)(Bt + (size_t)lr * H + lk);

    f32x4 z = {0.f, 0.f, 0.f, 0.f};
    f32x4 acc[4] = {z, z, z, z};

    for (int kc = 0; kc < H; kc += 32) {
        if (kc) __syncthreads();
        *(uint4*)&Abuf[lr * 40 + lk] = aR;
        *(uint4*)&Bbuf[lr * 40 + lk] = bR;
        __syncthreads();
        if (kc + 32 < H) {
            aR = *(const uint4*)(A + (size_t)lr * 512 + kc + 32 + lk);
            bR = *(const uint4*)(Bt + (size_t)lr * H + kc + 32 + lk);
        }
        const int q8 = (l >> 4) * 8;
        const short8 bf = *(const short8*)&Bbuf[(w * 16 + (l & 15)) * 40 + q8];
#pragma unroll
        for (int it = 0; it < 4; ++it) {
            const short8 af = *(const short8*)&Abuf[(it * 16 + (l & 15)) * 40 + q8];
            acc[it] = __builtin_amdgcn_mfma_f32_16x16x32_bf16(af, bf, acc[it], 0, 0, 0);
        }
    }

    const int n  = w * 16 + (l & 15);
    const int r0 = (l >> 4) * 4;
    const float bn = bias[n];
#pragma unroll
    for (int it = 0; it < 4; ++it)
#pragma unroll
        for (int r = 0; r < 4; ++r)
            C[(size_t)(it * 16 + r0 + r) * 256 + n] = f2bf(acc[it][r] + bn);
}

// ---------------- k3: scores (MFMA) + fused horizon expansion ---------------
// 64x64 score tile, grid (16,16,4). K = 128. Nontemporal stores for the
// 201 MB output stream (write-through, no L2 allocate).
__global__ __launch_bounds__(256) void k3_kernel(
    const unsigned short* __restrict__ od,
    const float* __restrict__ bbp, const float* __restrict__ wh,
    const float* __restrict__ bh, float* __restrict__ out)
{
    __shared__ unsigned short Abuf[64 * 40];
    __shared__ unsigned short Bbuf[64 * 40];
    const int tid = threadIdx.x;
    const int w  = tid >> 6;
    const int l  = tid & 63;
    const int lr = tid >> 2;
    const int lk = (tid & 3) * 8;
    const int b  = blockIdx.z;
    const int i0 = blockIdx.y * 64;
    const int j0 = blockIdx.x * 64;
    const unsigned short* Ab = od + ((size_t)b * N + i0) * 256;        // oW rows
    const unsigned short* Bb = od + ((size_t)b * N + j0) * 256 + 128;  // dd rows

    uint4 aR = *(const uint4*)(Ab + (size_t)lr * 256 + lk);
    uint4 bR = *(const uint4*)(Bb + (size_t)lr * 256 + lk);

    f32x4 z = {0.f, 0.f, 0.f, 0.f};
    f32x4 acc[4] = {z, z, z, z};

    for (int kc = 0; kc < H2; kc += 32) {
        if (kc) __syncthreads();
        *(uint4*)&Abuf[lr * 40 + lk] = aR;
        *(uint4*)&Bbuf[lr * 40 + lk] = bR;
        __syncthreads();
        if (kc + 32 < H2) {
            aR = *(const uint4*)(Ab + (size_t)lr * 256 + kc + 32 + lk);
            bR = *(const uint4*)(Bb + (size_t)lr * 256 + kc + 32 + lk);
        }
        const int q8 = (l >> 4) * 8;
        const short8 bf = *(const short8*)&Bbuf[(w * 16 + (l & 15)) * 40 + q8];
#pragma unroll
        for (int it = 0; it < 4; ++it) {
            const short8 af = *(const short8*)&Abuf[(it * 16 + (l & 15)) * 40 + q8];
            acc[it] = __builtin_amdgcn_mfma_f32_16x16x32_bf16(af, bf, acc[it], 0, 0, 0);
        }
    }

    const float bbv = bbp[0];
    float s[4][4];
#pragma unroll
    for (int it = 0; it < 4; ++it)
#pragma unroll
        for (int r = 0; r < 4; ++r) s[it][r] = acc[it][r] + bbv;

    const int jcol = j0 + w * 16 + (l & 15);
    const int r0   = (l >> 4) * 4;
    // out[((b*T+t)*N + i)*N + j]; 16 lanes per row = 64B full lines
#pragma unroll
    for (int t = 0; t < T; ++t) {
        const float wt = wh[t], bt = bh[t];
        float* ob = out + ((size_t)(b * T + t) * N + i0 + r0) * N + jcol;
#pragma unroll
        for (int it = 0; it < 4; ++it)
#pragma unroll
            for (int r = 0; r < 4; ++r)
                __builtin_nontemporal_store(
                    fmaxf(fmaf(s[it][r], wt, bt), 0.f),
                    ob + (size_t)(it * 16 + r) * N);
    }
}

extern "C" void kernel_launch(void* const* d_in, const int* in_sizes, int n_in,
                              void* d_out, int out_size, void* d_ws, size_t ws_size,
                              hipStream_t stream) {
    const float* x   = (const float*)d_in[0];
    const float* W1o = (const float*)d_in[1];
    const float* b1o = (const float*)d_in[2];
    const float* W2o = (const float*)d_in[3];
    const float* b2o = (const float*)d_in[4];
    const float* W1d = (const float*)d_in[5];
    const float* b1d = (const float*)d_in[6];
    const float* W2d = (const float*)d_in[7];
    const float* b2d = (const float*)d_in[8];
    const float* Wb  = (const float*)d_in[9];
    const float* bb  = (const float*)d_in[10];
    const float* wh  = (const float*)d_in[11];
    const float* bh  = (const float*)d_in[12];
    float* out = (float*)d_out;

    // workspace: fp32 biases, then bf16 tensors (16B-aligned)
    float* bias1 = (float*)d_ws;                      // 512
    float* bias2 = bias1 + 512;                       // 256
    unsigned short* W1T = (unsigned short*)(bias2 + 256);   // 512*256
    unsigned short* W2T = W1T + 512 * H;                    // 256*256
    unsigned short* h   = W2T + 256 * H;                    // M*512
    unsigned short* od  = h + (size_t)M * 512;              // M*256 = [oW|dd]

    prep_kernel<<<897, 256, 0, stream>>>(W1o, b1o, W2o, b2o, W1d, b1d,
                                         W2d, b2d, Wb, W1T, W2T, bias1, bias2);

    enc1_kernel<<<dim3(8, M / 64), 256, 0, stream>>>(x, W1T, bias1, h);

    enc2_kernel<<<dim3(4, M / 64), 256, 0, stream>>>(h, W2T, bias2, od);

    k3_kernel<<<dim3(N / 64, N / 64, B), 256, 0, stream>>>(od, bb, wh, bh, out);
}